// Round 12
// baseline (99.937 us; speedup 1.0000x reference)
//
#include <hip/hip_runtime.h>
#include <hip/hip_bf16.h>

#define CC 64
#define NN 4096   // H*W
#define MM 1024   // pooled pixels

typedef __attribute__((ext_vector_type(4))) short s4b;      // 4 bf16 = 2 VGPRs
typedef __attribute__((ext_vector_type(8))) short s8b;      // 8 bf16 = 4 VGPRs
typedef __attribute__((ext_vector_type(4))) float float4v;  // MFMA C/D frag

__device__ inline unsigned short f2bf(float f) {
    union { float f; unsigned u; } v; v.f = f;
    unsigned r = v.u + 0x7fff + ((v.u >> 16) & 1);   // RNE
    return (unsigned short)(r >> 16);
}

__device__ inline float4v mfma16(s4b a, s4b b, float4v c) {
#if __has_builtin(__builtin_amdgcn_mfma_f32_16x16x16bf16_1k)
    return __builtin_amdgcn_mfma_f32_16x16x16bf16_1k(a, b, c, 0, 0, 0);
#else
    float4v d;
    asm volatile("v_mfma_f32_16x16x16_bf16 %0, %1, %2, %3"
                 : "=v"(d) : "v"(a), "v"(b), "v"(c));
    return d;
#endif
}

__device__ inline float4v mfma32(s8b a, s8b b, float4v c) {
#if __has_builtin(__builtin_amdgcn_mfma_f32_16x16x32_bf16)
    return __builtin_amdgcn_mfma_f32_16x16x32_bf16(a, b, c, 0, 0, 0);
#else
    float4v d;
    asm volatile("v_mfma_f32_16x16x32_bf16 %0, %1, %2, %3"
                 : "=v"(d) : "v"(a), "v"(b), "v"(c));
    return d;
#endif
}

// ---------------------------------------------------------------------------
// prep_kernel v5 = v4 (MFMA conv, unchanged math) + XCD-pinned block swizzle:
// 1D grid 512; xcd = bid&7 owns batches {2*xcd, 2*xcd+1}, so phi/g land in
// XCD-local L2 and attn (same mapping) reads them locally. Bit-exact vs v4.
// Block 256 thr = 4 waves; LDS 25.1 KB.
// ---------------------------------------------------------------------------
__global__ __launch_bounds__(256) void prep_kernel(
    const float* __restrict__ x,
    const float* __restrict__ Wth,
    const float* __restrict__ Wph,
    const float* __restrict__ Wg,
    unsigned short* __restrict__ thT,
    unsigned short* __restrict__ phiP,
    unsigned short* __restrict__ gP)
{
    constexpr int XP = 72;   // xs pitch (shorts): 144B, 16B-aligned
    constexpr int DP = 49;   // bufD pitch (f32): bank-stride 17 (c-free)

    __shared__ __align__(16) union {
        unsigned short xs[128 * XP];   // 18.4 KB bf16 x-tile [px][ch]
        float bufD[128 * DP];          // 25.1 KB D [px][j=0..47]
    } sh;

    const int tid  = threadIdx.x;
    // XCD swizzle: batches {2k,2k+1} -> XCD k (consecutive ids round-robin)
    const int bid  = blockIdx.x;
    const int xcd  = bid & 7;
    const int idx  = bid >> 3;          // 0..63
    const int b    = xcd * 2 + (idx >> 5);
    const int hp   = idx & 31;          // row-pair: n = hp*128 + px
    const int lane = tid & 63;
    const int wv   = tid >> 6;          // 0..3
    const int c15  = lane & 15;
    const int quad = lane >> 4;
    const int n0row = hp * 128;

    // ---- W A-frags: A[m=o(tile t)=c15][k=c=s*32+quad*8+0..7] ----
    s8b wf[3][2];
    {
        const float* base0 = (c15 < 8) ? (Wth + c15 * 64)
                                       : (Wph + (c15 - 8) * 64);
        const float* base1 = Wg + c15 * 64;
        const float* base2 = Wg + (16 + c15) * 64;
        const float* bases[3] = {base0, base1, base2};
#pragma unroll
        for (int t = 0; t < 3; ++t) {
#pragma unroll
            for (int s = 0; s < 2; ++s) {
                const float* p = bases[t] + s * 32 + quad * 8;
                const float4 w0 = *(const float4*)p;
                const float4 w1 = *(const float4*)(p + 4);
                union { unsigned short us[8]; s8b v; } tmp;
                tmp.us[0] = f2bf(w0.x); tmp.us[1] = f2bf(w0.y);
                tmp.us[2] = f2bf(w0.z); tmp.us[3] = f2bf(w0.w);
                tmp.us[4] = f2bf(w1.x); tmp.us[5] = f2bf(w1.y);
                tmp.us[6] = f2bf(w1.z); tmp.us[7] = f2bf(w1.w);
                wf[t][s] = tmp.v;
            }
        }
    }

    // ---- stage x -> bf16 LDS [px][ch] (2 ch packed per b32 write) ----
    {
        const int spx = tid & 127;      // pixel
        const int chp = tid >> 7;       // channel sub-pair
        const float* xb = x + (size_t)b * CC * NN + n0row + spx;
#pragma unroll
        for (int i = 0; i < 16; ++i) {
            const int c0 = i * 4 + chp * 2;
            const float va = xb[(size_t)c0 * NN];
            const float vb = xb[(size_t)(c0 + 1) * NN];
            const unsigned pk = (unsigned)f2bf(va) |
                                ((unsigned)f2bf(vb) << 16);
            *(unsigned*)&sh.xs[spx * XP + c0] = pk;
        }
    }
    __syncthreads();

    // ---- MFMA: 2 px-tiles x 2 k-steps x 3 j-tiles per wave ----
    float4v acc[2][3];
#pragma unroll
    for (int tl = 0; tl < 2; ++tl)
#pragma unroll
        for (int t = 0; t < 3; ++t)
            acc[tl][t] = float4v{0.f, 0.f, 0.f, 0.f};

#pragma unroll
    for (int tl = 0; tl < 2; ++tl) {
        const int p0 = wv * 32 + tl * 16;
#pragma unroll
        for (int s = 0; s < 2; ++s) {
            union { uint4 u; s8b v; } bx;   // B[k=s*32+quad*8+j][n=px=c15]
            bx.u = *(const uint4*)&sh.xs[(p0 + c15) * XP + s * 32 + quad * 8];
#pragma unroll
            for (int t = 0; t < 3; ++t)
                acc[tl][t] = mfma32(wf[t][s], bx.v, acc[tl][t]);
        }
    }
    __syncthreads();   // all xs reads done before bufD overwrites

    // ---- D -> bufD[px][j]: D[m=t*16+quad*4+r][n=px=c15] ----
#pragma unroll
    for (int tl = 0; tl < 2; ++tl) {
        const int p0 = wv * 32 + tl * 16;
#pragma unroll
        for (int t = 0; t < 3; ++t)
#pragma unroll
            for (int r = 0; r < 4; ++r)
                sh.bufD[(p0 + c15) * DP + t * 16 + quad * 4 + r]
                    = acc[tl][t][r];
    }
    __syncthreads();

    // ---- theta store (x log2e, bf16, 16B/px contiguous) ----
    if (tid < 128) {
        const int px = tid;
        union { unsigned short s_[8]; uint4 v; } pk;
#pragma unroll
        for (int j = 0; j < 8; ++j)
            pk.s_[j] = f2bf(sh.bufD[px * DP + j] * 1.44269504f);
        *(uint4*)&thT[((size_t)b * NN + n0row + px) * 8] = pk.v;
    }

    // ---- 2x2 pool: 32 pooled cols x 40 channels ----
    for (int idx2 = tid; idx2 < 1280; idx2 += 256) {
        const int pm = idx2 & 31;       // pooled col
        const int jj = idx2 >> 5;       // 0..7 phi, 8..39 g
        const int p00 = 2 * pm, p10 = 64 + 2 * pm;
        const float v = fmaxf(
            fmaxf(sh.bufD[p00 * DP + 8 + jj], sh.bufD[(p00 + 1) * DP + 8 + jj]),
            fmaxf(sh.bufD[p10 * DP + 8 + jj], sh.bufD[(p10 + 1) * DP + 8 + jj]));
        const int m = hp * 32 + pm;
        if (jj < 8) phiP[((size_t)b * MM + m) * 8 + jj] = f2bf(v);
        else        gP[((size_t)b * 32 + (jj - 8)) * MM + m] = f2bf(v);
    }
}

// ---------------------------------------------------------------------------
// attn_mfma v9 = v8 + (a) XCD swizzle matching prep (batches {2k,2k+1} on
// XCD k -> phi/g L2-local) + (b) full-line epilogue: MFMA D goes to LDS
// obf[64][68] f32, then a float4 pass streams x/out in 256B-contiguous
// segments per 16-lane group (kills 64B partial-line RMW). Both changes are
// bit-exact (same FLOPs, same order). Grid 1024 (1D), block 256; LDS 31 KB.
// ---------------------------------------------------------------------------
__global__ __launch_bounds__(256) void attn_mfma(
    const unsigned short* __restrict__ thT,   // [B][N][8]
    const unsigned short* __restrict__ phiP,  // [B][M][8]
    const unsigned short* __restrict__ gP,    // [B][32][M]
    const float* __restrict__ x,
    const float* __restrict__ Wa,             // [64][32]
    const float* __restrict__ sigma,
    float* __restrict__ out)
{
    constexpr int GP  = 264;  // g_s pitch (bf16): 528 B = 33x16 -> aligned rows
    constexpr int OBP = 40;   // obb pitch (bf16): 80 B = 5x16 -> aligned rows
    constexpr int OFP = 68;   // obf pitch (f32): 272 B = 17x16 -> aligned rows

    __shared__ __align__(16) union {
        struct {
            unsigned short phi[256 * 8 + 16];  // pad: slot-255 quad2/3 overread
            unsigned short g[32 * GP];
        } m;                                    // 21.0 KB
        struct {
            float part[18][128];                // 9.2 KB (key-half partials)
            unsigned short obb[64 * OBP];       // 5.1 KB
            float obf[64][OFP];                 // 17.4 KB (epilogue f32 tile)
        } cb;                                   // 31.7 KB
    } sh;

    const int tid  = threadIdx.x;
    const int lane = tid & 63;
    const int wv   = tid >> 6;      // 0..3
    const int wq   = wv & 1;        // query-tile pair owner
    const int wk   = wv >> 1;       // key-parity half
    const int c15  = lane & 15;     // score D col = query; PV D col = gi
    const int quad = lane >> 4;
    // XCD swizzle matching prep: batches {2k,2k+1} -> XCD k
    const int bid  = blockIdx.x;
    const int xcd  = bid & 7;
    const int idx  = bid >> 3;          // 0..127
    const int b    = xcd * 2 + (idx >> 6);
    const int n0   = (idx & 63) * 64;

    // Wa A-frag in registers (epilogue): A[m=c15 -> o=wv*16+c15][k=quad*8+j]
    union { unsigned short s[8]; s8b v; } wfrag;
    {
        const float* wr = Wa + (wv * 16 + c15) * 32 + quad * 8;
        const float4 w0 = *(const float4*)wr;
        const float4 w1 = *(const float4*)(wr + 4);
        wfrag.s[0] = f2bf(w0.x); wfrag.s[1] = f2bf(w0.y);
        wfrag.s[2] = f2bf(w0.z); wfrag.s[3] = f2bf(w0.w);
        wfrag.s[4] = f2bf(w1.x); wfrag.s[5] = f2bf(w1.y);
        wfrag.s[6] = f2bf(w1.z); wfrag.s[7] = f2bf(w1.w);
    }

    // theta B-frags for both owned query tiles: B[k=quad*4+j][n=q]
    s4b zero4 = {0, 0, 0, 0};
    s4b bthA = zero4, bthB = zero4;
    if (quad < 2) {
        union { uint2 u; s4b s; } t;
        t.u = *(const uint2*)&thT[((size_t)b * NN + n0 + wq * 32 + c15) * 8 + quad * 4];
        bthA = t.s;
        t.u = *(const uint2*)&thT[((size_t)b * NN + n0 + wq * 32 + 16 + c15) * 8 + quad * 4];
        bthB = t.s;
    }

    float4v accA0 = {0.f, 0.f, 0.f, 0.f};
    float4v accA1 = {0.f, 0.f, 0.f, 0.f};
    float4v accB0 = {0.f, 0.f, 0.f, 0.f};
    float4v accB1 = {0.f, 0.f, 0.f, 0.f};
    float zaccA = 0.f, zaccB = 0.f;

    const int wk4 = wk * 4;

    // staging-address components (constant across chunks)
    const int sl_r  = tid & 7;
    const int sl_q3 = (tid >> 3) & 3;
    const int slot  = (tid & ~31) | ((sl_r >> 2) << 4) | (sl_q3 << 2) | (sl_r & 3);
    const size_t phi_base = ((size_t)b * MM + tid) * 8;        // + ch*256*8
    size_t g_base[4];
    int    g_dst[4];
#pragma unroll
    for (int it = 0; it < 4; ++it) {
        const int idx2 = tid + 256 * it;
        const int grow = idx2 >> 5, c32 = idx2 & 31;
        g_base[it] = ((size_t)b * 32 + grow) * MM + c32 * 8;   // + ch*256
        g_dst[it]  = grow * GP + c32 * 8;
    }

    // T14 prologue: chunk-0 loads into registers
    uint4 rphi = *(const uint4*)&phiP[phi_base];
    uint4 rg0  = *(const uint4*)&gP[g_base[0]];
    uint4 rg1  = *(const uint4*)&gP[g_base[1]];
    uint4 rg2  = *(const uint4*)&gP[g_base[2]];
    uint4 rg3  = *(const uint4*)&gP[g_base[3]];

    for (int ch = 0; ch < 4; ++ch) {
        __syncthreads();   // prior chunk's LDS reads complete
        // ds_write staged registers (phi slot-permuted, g linear) + pads
        *(uint4*)&sh.m.phi[slot * 8] = rphi;
        if (tid < 2) {
            uint4 z4; z4.x = z4.y = z4.z = z4.w = 0u;
            *(uint4*)&sh.m.phi[256 * 8 + tid * 8] = z4;
        }
        *(uint4*)&sh.m.g[g_dst[0]] = rg0;
        *(uint4*)&sh.m.g[g_dst[1]] = rg1;
        *(uint4*)&sh.m.g[g_dst[2]] = rg2;
        *(uint4*)&sh.m.g[g_dst[3]] = rg3;
        // issue NEXT chunk's loads now -- latency hides under compute below
        if (ch < 3) {
            const size_t co = (size_t)(ch + 1) * 256;
            rphi = *(const uint4*)&phiP[phi_base + co * 8];
            rg0  = *(const uint4*)&gP[g_base[0] + co];
            rg1  = *(const uint4*)&gP[g_base[1] + co];
            rg2  = *(const uint4*)&gP[g_base[2] + co];
            rg3  = *(const uint4*)&gP[g_base[3] + co];
        }
        __syncthreads();   // staging visible

        const unsigned short* pA  = &sh.m.phi[c15 * 8 + quad * 4];
        const unsigned short* pg0 = &sh.m.g[c15 * GP + quad * 8];
        const unsigned short* pg1 = pg0 + 16 * GP;

#pragma unroll
        for (int s = 0; s < 4; ++s) {
            const int g32 = wk4 + s;   // this wave's key-parity half

            union { uint2 u; s4b s_; } apA, apB;
            apA.u = *(const uint2*)&pA[g32 * 256];
            apB.u = *(const uint2*)&pA[g32 * 256 + 128];

            float4v cz = {0.f, 0.f, 0.f, 0.f};
            float4v sAlo = mfma16(apA.s_, bthA, cz);  // D[key=quad*8+r][qA=c15]
            float4v sAhi = mfma16(apB.s_, bthA, cz);  // keys +4..7
            float4v sBlo = mfma16(apA.s_, bthB, cz);
            float4v sBhi = mfma16(apB.s_, bthB, cz);

            union { float f; unsigned u; } a0, a1, a2, a3, b0, b1, b2, b3;
            a0.f = __builtin_amdgcn_exp2f(sAlo[0]);
            a1.f = __builtin_amdgcn_exp2f(sAlo[1]);
            a2.f = __builtin_amdgcn_exp2f(sAlo[2]);
            a3.f = __builtin_amdgcn_exp2f(sAlo[3]);
            b0.f = __builtin_amdgcn_exp2f(sAhi[0]);
            b1.f = __builtin_amdgcn_exp2f(sAhi[1]);
            b2.f = __builtin_amdgcn_exp2f(sAhi[2]);
            b3.f = __builtin_amdgcn_exp2f(sAhi[3]);
            zaccA += ((a0.f + a1.f) + (a2.f + a3.f)) +
                     ((b0.f + b1.f) + (b2.f + b3.f));
            union { uint4 u; s8b s_; } paA;
            paA.u.x = __builtin_amdgcn_perm(a1.u, a0.u, 0x07060302u);
            paA.u.y = __builtin_amdgcn_perm(a3.u, a2.u, 0x07060302u);
            paA.u.z = __builtin_amdgcn_perm(b1.u, b0.u, 0x07060302u);
            paA.u.w = __builtin_amdgcn_perm(b3.u, b2.u, 0x07060302u);

            a0.f = __builtin_amdgcn_exp2f(sBlo[0]);
            a1.f = __builtin_amdgcn_exp2f(sBlo[1]);
            a2.f = __builtin_amdgcn_exp2f(sBlo[2]);
            a3.f = __builtin_amdgcn_exp2f(sBlo[3]);
            b0.f = __builtin_amdgcn_exp2f(sBhi[0]);
            b1.f = __builtin_amdgcn_exp2f(sBhi[1]);
            b2.f = __builtin_amdgcn_exp2f(sBhi[2]);
            b3.f = __builtin_amdgcn_exp2f(sBhi[3]);
            zaccB += ((a0.f + a1.f) + (a2.f + a3.f)) +
                     ((b0.f + b1.f) + (b2.f + b3.f));
            union { uint4 u; s8b s_; } paB;
            paB.u.x = __builtin_amdgcn_perm(a1.u, a0.u, 0x07060302u);
            paB.u.y = __builtin_amdgcn_perm(a3.u, a2.u, 0x07060302u);
            paB.u.z = __builtin_amdgcn_perm(b1.u, b0.u, 0x07060302u);
            paB.u.w = __builtin_amdgcn_perm(b3.u, b2.u, 0x07060302u);

            union { uint4 u; s8b s_; } bg0, bg1;
            bg0.u = *(const uint4*)&pg0[g32 * 32];
            bg1.u = *(const uint4*)&pg1[g32 * 32];

            accA0 = mfma32(paA.s_, bg0.s_, accA0);   // D[q=quad*4+r][gi=c15]
            accA1 = mfma32(paA.s_, bg1.s_, accA1);   // gi = c15+16
            accB0 = mfma32(paB.s_, bg0.s_, accB0);
            accB1 = mfma32(paB.s_, bg1.s_, accB1);
        }
    }

    // ---- key-half combine: wk=1 waves dump partials; wk=0 fold them in ----
    __syncthreads();                       // all staging reads complete
    if (wk == 1) {
#pragma unroll
        for (int r = 0; r < 4; ++r) {
            sh.cb.part[     r][wq * 64 + lane] = accA0[r];
            sh.cb.part[ 4 + r][wq * 64 + lane] = accA1[r];
            sh.cb.part[ 8 + r][wq * 64 + lane] = accB0[r];
            sh.cb.part[12 + r][wq * 64 + lane] = accB1[r];
        }
        sh.cb.part[16][wq * 64 + lane] = zaccA;
        sh.cb.part[17][wq * 64 + lane] = zaccB;
    }
    __syncthreads();

    if (wk == 0) {
#pragma unroll
        for (int r = 0; r < 4; ++r) {
            accA0[r] += sh.cb.part[     r][wq * 64 + lane];
            accA1[r] += sh.cb.part[ 4 + r][wq * 64 + lane];
            accB0[r] += sh.cb.part[ 8 + r][wq * 64 + lane];
            accB1[r] += sh.cb.part[12 + r][wq * 64 + lane];
        }
        zaccA += sh.cb.part[16][wq * 64 + lane];
        zaccB += sh.cb.part[17][wq * 64 + lane];

        float zA = zaccA, zB = zaccB;
        zA += __shfl_xor(zA, 16, 64);
        zA += __shfl_xor(zA, 32, 64);
        zB += __shfl_xor(zB, 16, 64);
        zB += __shfl_xor(zB, 32, 64);
        const float rzqA = __builtin_amdgcn_rcpf(zA);
        const float rzqB = __builtin_amdgcn_rcpf(zB);

        // obar -> bf16 LDS rows [q][gi], pitch 40 (wv0: tiles 0,1; wv1: 2,3)
#pragma unroll
        for (int r = 0; r < 4; ++r) {
            const float rzA = __shfl(rzqA, quad * 4 + r, 64);
            const float rzB = __shfl(rzqB, quad * 4 + r, 64);
            const int qlA = wq * 32 + quad * 4 + r;
            const int qlB = qlA + 16;
            sh.cb.obb[qlA * OBP + c15]      = f2bf(accA0[r] * rzA);
            sh.cb.obb[qlA * OBP + 16 + c15] = f2bf(accA1[r] * rzA);
            sh.cb.obb[qlB * OBP + c15]      = f2bf(accB0[r] * rzB);
            sh.cb.obb[qlB * OBP + 16 + c15] = f2bf(accB1[r] * rzB);
        }
    }
    __syncthreads();

    // epilogue stage 1: MFMA -> LDS obf[o][q] f32 (obf disjoint from obb)
#pragma unroll
    for (int t = 0; t < 4; ++t) {
        union { uint4 u; s8b s_; } bo;
        bo.u = *(const uint4*)&sh.cb.obb[(t * 16 + c15) * OBP + quad * 8];
        float4v cz = {0.f, 0.f, 0.f, 0.f};
        float4v oc = mfma32(wfrag.v, bo.s_, cz);  // D[o=wv*16+quad*4+r][q=c15]
#pragma unroll
        for (int r = 0; r < 4; ++r)
            sh.cb.obf[wv * 16 + quad * 4 + r][t * 16 + c15] = oc[r];
    }
    __syncthreads();

    // epilogue stage 2: full-line streaming. 16 lanes x float4 = 256B
    // contiguous per row segment; nontemporal (read-once/write-once).
    const float sg = sigma[0];
    const int orow = tid >> 4;          // 0..15 (+ p*16)
    const int c4   = (tid & 15) * 4;
#pragma unroll
    for (int p = 0; p < 4; ++p) {
        const int o = p * 16 + orow;
        const float* of = &sh.cb.obf[o][c4];
        const size_t oi = ((size_t)b * CC + o) * NN + n0 + c4;
        float4 xv_;
        xv_.x = __builtin_nontemporal_load(&x[oi]);
        xv_.y = __builtin_nontemporal_load(&x[oi + 1]);
        xv_.z = __builtin_nontemporal_load(&x[oi + 2]);
        xv_.w = __builtin_nontemporal_load(&x[oi + 3]);
        __builtin_nontemporal_store(xv_.x + sg * of[0], &out[oi]);
        __builtin_nontemporal_store(xv_.y + sg * of[1], &out[oi + 1]);
        __builtin_nontemporal_store(xv_.z + sg * of[2], &out[oi + 2]);
        __builtin_nontemporal_store(xv_.w + sg * of[3], &out[oi + 3]);
    }
}

extern "C" void kernel_launch(void* const* d_in, const int* in_sizes, int n_in,
                              void* d_out, int out_size, void* d_ws, size_t ws_size,
                              hipStream_t stream) {
    const float* x      = (const float*)d_in[0];
    const float* W_th   = (const float*)d_in[1];
    const float* W_ph   = (const float*)d_in[2];
    const float* W_g    = (const float*)d_in[3];
    const float* W_attn = (const float*)d_in[4];
    const float* sigma  = (const float*)d_in[5];
    float* out = (float*)d_out;

    const int B = 16;
    unsigned short* thT  = (unsigned short*)d_ws;              // B*N*8
    unsigned short* phiP = thT + (size_t)B * NN * 8;           // B*M*8
    unsigned short* gP   = phiP + (size_t)B * MM * 8;          // B*32*M

    prep_kernel<<<dim3(512), 256, 0, stream>>>(x, W_th, W_ph, W_g,
                                               thT, phiP, gP);
    attn_mfma<<<dim3(1024), 256, 0, stream>>>(thT, phiP, gP, x,
                                              W_attn, sigma, out);
}

// Round 13
// 97.921 us; speedup vs baseline: 1.0206x; 1.0206x over previous
//
#include <hip/hip_runtime.h>
#include <hip/hip_bf16.h>

#define CC 64
#define NN 4096   // H*W
#define MM 1024   // pooled pixels

typedef __attribute__((ext_vector_type(4))) short s4b;      // 4 bf16 = 2 VGPRs
typedef __attribute__((ext_vector_type(8))) short s8b;      // 8 bf16 = 4 VGPRs
typedef __attribute__((ext_vector_type(4))) float float4v;  // MFMA C/D frag

__device__ inline unsigned short f2bf(float f) {
    union { float f; unsigned u; } v; v.f = f;
    unsigned r = v.u + 0x7fff + ((v.u >> 16) & 1);   // RNE
    return (unsigned short)(r >> 16);
}

__device__ inline float4v mfma16(s4b a, s4b b, float4v c) {
#if __has_builtin(__builtin_amdgcn_mfma_f32_16x16x16bf16_1k)
    return __builtin_amdgcn_mfma_f32_16x16x16bf16_1k(a, b, c, 0, 0, 0);
#else
    float4v d;
    asm volatile("v_mfma_f32_16x16x16_bf16 %0, %1, %2, %3"
                 : "=v"(d) : "v"(a), "v"(b), "v"(c));
    return d;
#endif
}

__device__ inline float4v mfma32(s8b a, s8b b, float4v c) {
#if __has_builtin(__builtin_amdgcn_mfma_f32_16x16x32_bf16)
    return __builtin_amdgcn_mfma_f32_16x16x32_bf16(a, b, c, 0, 0, 0);
#else
    float4v d;
    asm volatile("v_mfma_f32_16x16x32_bf16 %0, %1, %2, %3"
                 : "=v"(d) : "v"(a), "v"(b), "v"(c));
    return d;
#endif
}

// ---------------------------------------------------------------------------
// prep_kernel v4 (R10 win, reverted to exact R11 config): MFMA conv.
// D[48 out][128 px] = W[48][64] . x[64][128 px] per block via 16x16x32.
// Block 256 thr = 4 waves; grid (32,16); LDS 25.1 KB.
// ---------------------------------------------------------------------------
__global__ __launch_bounds__(256) void prep_kernel(
    const float* __restrict__ x,
    const float* __restrict__ Wth,
    const float* __restrict__ Wph,
    const float* __restrict__ Wg,
    unsigned short* __restrict__ thT,
    unsigned short* __restrict__ phiP,
    unsigned short* __restrict__ gP)
{
    constexpr int XP = 72;   // xs pitch (shorts): 144B, 16B-aligned
    constexpr int DP = 49;   // bufD pitch (f32): bank-stride 17 (c-free)

    __shared__ __align__(16) union {
        unsigned short xs[128 * XP];   // 18.4 KB bf16 x-tile [px][ch]
        float bufD[128 * DP];          // 25.1 KB D [px][j=0..47]
    } sh;

    const int tid  = threadIdx.x;
    const int b    = blockIdx.y;
    const int hp   = blockIdx.x;        // row-pair: n = hp*128 + px
    const int lane = tid & 63;
    const int wv   = tid >> 6;          // 0..3
    const int c15  = lane & 15;
    const int quad = lane >> 4;
    const int n0row = hp * 128;

    // ---- W A-frags: A[m=o(tile t)=c15][k=c=s*32+quad*8+0..7] ----
    s8b wf[3][2];
    {
        const float* base0 = (c15 < 8) ? (Wth + c15 * 64)
                                       : (Wph + (c15 - 8) * 64);
        const float* base1 = Wg + c15 * 64;
        const float* base2 = Wg + (16 + c15) * 64;
        const float* bases[3] = {base0, base1, base2};
#pragma unroll
        for (int t = 0; t < 3; ++t) {
#pragma unroll
            for (int s = 0; s < 2; ++s) {
                const float* p = bases[t] + s * 32 + quad * 8;
                const float4 w0 = *(const float4*)p;
                const float4 w1 = *(const float4*)(p + 4);
                union { unsigned short us[8]; s8b v; } tmp;
                tmp.us[0] = f2bf(w0.x); tmp.us[1] = f2bf(w0.y);
                tmp.us[2] = f2bf(w0.z); tmp.us[3] = f2bf(w0.w);
                tmp.us[4] = f2bf(w1.x); tmp.us[5] = f2bf(w1.y);
                tmp.us[6] = f2bf(w1.z); tmp.us[7] = f2bf(w1.w);
                wf[t][s] = tmp.v;
            }
        }
    }

    // ---- stage x -> bf16 LDS [px][ch] (2 ch packed per b32 write) ----
    {
        const int spx = tid & 127;      // pixel
        const int chp = tid >> 7;       // channel sub-pair
        const float* xb = x + (size_t)b * CC * NN + n0row + spx;
#pragma unroll
        for (int i = 0; i < 16; ++i) {
            const int c0 = i * 4 + chp * 2;
            const float va = xb[(size_t)c0 * NN];
            const float vb = xb[(size_t)(c0 + 1) * NN];
            const unsigned pk = (unsigned)f2bf(va) |
                                ((unsigned)f2bf(vb) << 16);
            *(unsigned*)&sh.xs[spx * XP + c0] = pk;
        }
    }
    __syncthreads();

    // ---- MFMA: 2 px-tiles x 2 k-steps x 3 j-tiles per wave ----
    float4v acc[2][3];
#pragma unroll
    for (int tl = 0; tl < 2; ++tl)
#pragma unroll
        for (int t = 0; t < 3; ++t)
            acc[tl][t] = float4v{0.f, 0.f, 0.f, 0.f};

#pragma unroll
    for (int tl = 0; tl < 2; ++tl) {
        const int p0 = wv * 32 + tl * 16;
#pragma unroll
        for (int s = 0; s < 2; ++s) {
            union { uint4 u; s8b v; } bx;   // B[k=s*32+quad*8+j][n=px=c15]
            bx.u = *(const uint4*)&sh.xs[(p0 + c15) * XP + s * 32 + quad * 8];
#pragma unroll
            for (int t = 0; t < 3; ++t)
                acc[tl][t] = mfma32(wf[t][s], bx.v, acc[tl][t]);
        }
    }
    __syncthreads();   // all xs reads done before bufD overwrites

    // ---- D -> bufD[px][j]: D[m=t*16+quad*4+r][n=px=c15] ----
#pragma unroll
    for (int tl = 0; tl < 2; ++tl) {
        const int p0 = wv * 32 + tl * 16;
#pragma unroll
        for (int t = 0; t < 3; ++t)
#pragma unroll
            for (int r = 0; r < 4; ++r)
                sh.bufD[(p0 + c15) * DP + t * 16 + quad * 4 + r]
                    = acc[tl][t][r];
    }
    __syncthreads();

    // ---- theta store (x log2e, bf16, 16B/px contiguous) ----
    if (tid < 128) {
        const int px = tid;
        union { unsigned short s_[8]; uint4 v; } pk;
#pragma unroll
        for (int j = 0; j < 8; ++j)
            pk.s_[j] = f2bf(sh.bufD[px * DP + j] * 1.44269504f);
        *(uint4*)&thT[((size_t)b * NN + n0row + px) * 8] = pk.v;
    }

    // ---- 2x2 pool: 32 pooled cols x 40 channels ----
    for (int idx = tid; idx < 1280; idx += 256) {
        const int pm = idx & 31;        // pooled col
        const int jj = idx >> 5;        // 0..7 phi, 8..39 g
        const int p00 = 2 * pm, p10 = 64 + 2 * pm;
        const float v = fmaxf(
            fmaxf(sh.bufD[p00 * DP + 8 + jj], sh.bufD[(p00 + 1) * DP + 8 + jj]),
            fmaxf(sh.bufD[p10 * DP + 8 + jj], sh.bufD[(p10 + 1) * DP + 8 + jj]));
        const int m = hp * 32 + pm;
        if (jj < 8) phiP[((size_t)b * MM + m) * 8 + jj] = f2bf(v);
        else        gP[((size_t)b * 32 + (jj - 8)) * MM + m] = f2bf(v);
    }
}

// ---------------------------------------------------------------------------
// attn_mfma v8 (R11 best, reverted verbatim): v7 key-parity split + T14
// async-STAGE register pipeline + nontemporal epilogue. R12's XCD swizzle
// and LDS full-line epilogue both regressed (-2 µs) and are dropped.
// Grid (64,16), block 256; LDS 21 KB; 4 blocks/CU.
// ---------------------------------------------------------------------------
__global__ __launch_bounds__(256) void attn_mfma(
    const unsigned short* __restrict__ thT,   // [B][N][8]
    const unsigned short* __restrict__ phiP,  // [B][M][8]
    const unsigned short* __restrict__ gP,    // [B][32][M]
    const float* __restrict__ x,
    const float* __restrict__ Wa,             // [64][32]
    const float* __restrict__ sigma,
    float* __restrict__ out)
{
    constexpr int GP = 264;   // g_s pitch (bf16): 528 B = 33x16 -> aligned rows
    constexpr int OBP = 40;   // obb pitch (bf16): 80 B = 5x16 -> aligned rows

    __shared__ __align__(16) union {
        struct {
            unsigned short phi[256 * 8 + 16];  // pad: slot-255 quad2/3 overread
            unsigned short g[32 * GP];
        } m;                                    // 21.0 KB
        struct {
            float part[18][128];                // 9.2 KB (key-half partials)
            unsigned short obb[64 * OBP];       // 5.1 KB
        } cb;                                   // 14.3 KB
    } sh;

    const int tid  = threadIdx.x;
    const int lane = tid & 63;
    const int wv   = tid >> 6;      // 0..3
    const int wq   = wv & 1;        // query-tile pair owner
    const int wk   = wv >> 1;       // key-parity half
    const int c15  = lane & 15;     // score D col = query; PV D col = gi
    const int quad = lane >> 4;
    const int b    = blockIdx.y;
    const int n0   = blockIdx.x * 64;

    // Wa A-frag in registers (epilogue): A[m=c15 -> o=wv*16+c15][k=quad*8+j]
    union { unsigned short s[8]; s8b v; } wfrag;
    {
        const float* wr = Wa + (wv * 16 + c15) * 32 + quad * 8;
        const float4 w0 = *(const float4*)wr;
        const float4 w1 = *(const float4*)(wr + 4);
        wfrag.s[0] = f2bf(w0.x); wfrag.s[1] = f2bf(w0.y);
        wfrag.s[2] = f2bf(w0.z); wfrag.s[3] = f2bf(w0.w);
        wfrag.s[4] = f2bf(w1.x); wfrag.s[5] = f2bf(w1.y);
        wfrag.s[6] = f2bf(w1.z); wfrag.s[7] = f2bf(w1.w);
    }

    // theta B-frags for both owned query tiles: B[k=quad*4+j][n=q]
    s4b zero4 = {0, 0, 0, 0};
    s4b bthA = zero4, bthB = zero4;
    if (quad < 2) {
        union { uint2 u; s4b s; } t;
        t.u = *(const uint2*)&thT[((size_t)b * NN + n0 + wq * 32 + c15) * 8 + quad * 4];
        bthA = t.s;
        t.u = *(const uint2*)&thT[((size_t)b * NN + n0 + wq * 32 + 16 + c15) * 8 + quad * 4];
        bthB = t.s;
    }

    float4v accA0 = {0.f, 0.f, 0.f, 0.f};
    float4v accA1 = {0.f, 0.f, 0.f, 0.f};
    float4v accB0 = {0.f, 0.f, 0.f, 0.f};
    float4v accB1 = {0.f, 0.f, 0.f, 0.f};
    float zaccA = 0.f, zaccB = 0.f;

    const int wk4 = wk * 4;

    // staging-address components (constant across chunks)
    const int sl_r  = tid & 7;
    const int sl_q3 = (tid >> 3) & 3;
    const int slot  = (tid & ~31) | ((sl_r >> 2) << 4) | (sl_q3 << 2) | (sl_r & 3);
    const size_t phi_base = ((size_t)b * MM + tid) * 8;        // + ch*256*8
    size_t g_base[4];
    int    g_dst[4];
#pragma unroll
    for (int it = 0; it < 4; ++it) {
        const int idx  = tid + 256 * it;
        const int grow = idx >> 5, c32 = idx & 31;
        g_base[it] = ((size_t)b * 32 + grow) * MM + c32 * 8;   // + ch*256
        g_dst[it]  = grow * GP + c32 * 8;
    }

    // T14 prologue: chunk-0 loads into registers
    uint4 rphi = *(const uint4*)&phiP[phi_base];
    uint4 rg0  = *(const uint4*)&gP[g_base[0]];
    uint4 rg1  = *(const uint4*)&gP[g_base[1]];
    uint4 rg2  = *(const uint4*)&gP[g_base[2]];
    uint4 rg3  = *(const uint4*)&gP[g_base[3]];

    for (int ch = 0; ch < 4; ++ch) {
        __syncthreads();   // prior chunk's LDS reads complete
        // ds_write staged registers (phi slot-permuted, g linear) + pads
        *(uint4*)&sh.m.phi[slot * 8] = rphi;
        if (tid < 2) {
            uint4 z4; z4.x = z4.y = z4.z = z4.w = 0u;
            *(uint4*)&sh.m.phi[256 * 8 + tid * 8] = z4;
        }
        *(uint4*)&sh.m.g[g_dst[0]] = rg0;
        *(uint4*)&sh.m.g[g_dst[1]] = rg1;
        *(uint4*)&sh.m.g[g_dst[2]] = rg2;
        *(uint4*)&sh.m.g[g_dst[3]] = rg3;
        // issue NEXT chunk's loads now -- latency hides under compute below
        if (ch < 3) {
            const size_t co = (size_t)(ch + 1) * 256;
            rphi = *(const uint4*)&phiP[phi_base + co * 8];
            rg0  = *(const uint4*)&gP[g_base[0] + co];
            rg1  = *(const uint4*)&gP[g_base[1] + co];
            rg2  = *(const uint4*)&gP[g_base[2] + co];
            rg3  = *(const uint4*)&gP[g_base[3] + co];
        }
        __syncthreads();   // staging visible

        const unsigned short* pA  = &sh.m.phi[c15 * 8 + quad * 4];
        const unsigned short* pg0 = &sh.m.g[c15 * GP + quad * 8];
        const unsigned short* pg1 = pg0 + 16 * GP;

#pragma unroll
        for (int s = 0; s < 4; ++s) {
            const int g32 = wk4 + s;   // this wave's key-parity half

            union { uint2 u; s4b s_; } apA, apB;
            apA.u = *(const uint2*)&pA[g32 * 256];
            apB.u = *(const uint2*)&pA[g32 * 256 + 128];

            float4v cz = {0.f, 0.f, 0.f, 0.f};
            float4v sAlo = mfma16(apA.s_, bthA, cz);  // D[key=quad*8+r][qA=c15]
            float4v sAhi = mfma16(apB.s_, bthA, cz);  // keys +4..7
            float4v sBlo = mfma16(apA.s_, bthB, cz);
            float4v sBhi = mfma16(apB.s_, bthB, cz);

            union { float f; unsigned u; } a0, a1, a2, a3, b0, b1, b2, b3;
            a0.f = __builtin_amdgcn_exp2f(sAlo[0]);
            a1.f = __builtin_amdgcn_exp2f(sAlo[1]);
            a2.f = __builtin_amdgcn_exp2f(sAlo[2]);
            a3.f = __builtin_amdgcn_exp2f(sAlo[3]);
            b0.f = __builtin_amdgcn_exp2f(sAhi[0]);
            b1.f = __builtin_amdgcn_exp2f(sAhi[1]);
            b2.f = __builtin_amdgcn_exp2f(sAhi[2]);
            b3.f = __builtin_amdgcn_exp2f(sAhi[3]);
            zaccA += ((a0.f + a1.f) + (a2.f + a3.f)) +
                     ((b0.f + b1.f) + (b2.f + b3.f));
            union { uint4 u; s8b s_; } paA;
            paA.u.x = __builtin_amdgcn_perm(a1.u, a0.u, 0x07060302u);
            paA.u.y = __builtin_amdgcn_perm(a3.u, a2.u, 0x07060302u);
            paA.u.z = __builtin_amdgcn_perm(b1.u, b0.u, 0x07060302u);
            paA.u.w = __builtin_amdgcn_perm(b3.u, b2.u, 0x07060302u);

            a0.f = __builtin_amdgcn_exp2f(sBlo[0]);
            a1.f = __builtin_amdgcn_exp2f(sBlo[1]);
            a2.f = __builtin_amdgcn_exp2f(sBlo[2]);
            a3.f = __builtin_amdgcn_exp2f(sBlo[3]);
            b0.f = __builtin_amdgcn_exp2f(sBhi[0]);
            b1.f = __builtin_amdgcn_exp2f(sBhi[1]);
            b2.f = __builtin_amdgcn_exp2f(sBhi[2]);
            b3.f = __builtin_amdgcn_exp2f(sBhi[3]);
            zaccB += ((a0.f + a1.f) + (a2.f + a3.f)) +
                     ((b0.f + b1.f) + (b2.f + b3.f));
            union { uint4 u; s8b s_; } paB;
            paB.u.x = __builtin_amdgcn_perm(a1.u, a0.u, 0x07060302u);
            paB.u.y = __builtin_amdgcn_perm(a3.u, a2.u, 0x07060302u);
            paB.u.z = __builtin_amdgcn_perm(b1.u, b0.u, 0x07060302u);
            paB.u.w = __builtin_amdgcn_perm(b3.u, b2.u, 0x07060302u);

            union { uint4 u; s8b s_; } bg0, bg1;
            bg0.u = *(const uint4*)&pg0[g32 * 32];
            bg1.u = *(const uint4*)&pg1[g32 * 32];

            accA0 = mfma32(paA.s_, bg0.s_, accA0);   // D[q=quad*4+r][gi=c15]
            accA1 = mfma32(paA.s_, bg1.s_, accA1);   // gi = c15+16
            accB0 = mfma32(paB.s_, bg0.s_, accB0);
            accB1 = mfma32(paB.s_, bg1.s_, accB1);
        }
    }

    // ---- key-half combine: wk=1 waves dump partials; wk=0 fold them in ----
    __syncthreads();                       // all staging reads complete
    if (wk == 1) {
#pragma unroll
        for (int r = 0; r < 4; ++r) {
            sh.cb.part[     r][wq * 64 + lane] = accA0[r];
            sh.cb.part[ 4 + r][wq * 64 + lane] = accA1[r];
            sh.cb.part[ 8 + r][wq * 64 + lane] = accB0[r];
            sh.cb.part[12 + r][wq * 64 + lane] = accB1[r];
        }
        sh.cb.part[16][wq * 64 + lane] = zaccA;
        sh.cb.part[17][wq * 64 + lane] = zaccB;
    }
    __syncthreads();

    if (wk == 0) {
#pragma unroll
        for (int r = 0; r < 4; ++r) {
            accA0[r] += sh.cb.part[     r][wq * 64 + lane];
            accA1[r] += sh.cb.part[ 4 + r][wq * 64 + lane];
            accB0[r] += sh.cb.part[ 8 + r][wq * 64 + lane];
            accB1[r] += sh.cb.part[12 + r][wq * 64 + lane];
        }
        zaccA += sh.cb.part[16][wq * 64 + lane];
        zaccB += sh.cb.part[17][wq * 64 + lane];

        float zA = zaccA, zB = zaccB;
        zA += __shfl_xor(zA, 16, 64);
        zA += __shfl_xor(zA, 32, 64);
        zB += __shfl_xor(zB, 16, 64);
        zB += __shfl_xor(zB, 32, 64);
        const float rzqA = __builtin_amdgcn_rcpf(zA);
        const float rzqB = __builtin_amdgcn_rcpf(zB);

        // obar -> bf16 LDS rows [q][gi], pitch 40 (wv0: tiles 0,1; wv1: 2,3)
#pragma unroll
        for (int r = 0; r < 4; ++r) {
            const float rzA = __shfl(rzqA, quad * 4 + r, 64);
            const float rzB = __shfl(rzqB, quad * 4 + r, 64);
            const int qlA = wq * 32 + quad * 4 + r;
            const int qlB = qlA + 16;
            sh.cb.obb[qlA * OBP + c15]      = f2bf(accA0[r] * rzA);
            sh.cb.obb[qlA * OBP + 16 + c15] = f2bf(accA1[r] * rzA);
            sh.cb.obb[qlB * OBP + c15]      = f2bf(accB0[r] * rzB);
            sh.cb.obb[qlB * OBP + 16 + c15] = f2bf(accB1[r] * rzB);
        }
    }
    __syncthreads();

    // epilogue: out[o][q] = x + sigma * Wa[o].obar[q]  (nontemporal streams)
    const float sg = sigma[0];
#pragma unroll
    for (int t = 0; t < 4; ++t) {
        union { uint4 u; s8b s_; } bo;
        bo.u = *(const uint4*)&sh.cb.obb[(t * 16 + c15) * OBP + quad * 8];
        float4v cz = {0.f, 0.f, 0.f, 0.f};
        float4v oc = mfma32(wfrag.v, bo.s_, cz);  // D[o=wv*16+quad*4+r][q=c15]
#pragma unroll
        for (int r = 0; r < 4; ++r) {
            const size_t oi = ((size_t)b * CC + wv * 16 + quad * 4 + r) * NN
                              + n0 + t * 16 + c15;
            const float xv_ = __builtin_nontemporal_load(&x[oi]);
            __builtin_nontemporal_store(xv_ + sg * oc[r], &out[oi]);
        }
    }
}

extern "C" void kernel_launch(void* const* d_in, const int* in_sizes, int n_in,
                              void* d_out, int out_size, void* d_ws, size_t ws_size,
                              hipStream_t stream) {
    const float* x      = (const float*)d_in[0];
    const float* W_th   = (const float*)d_in[1];
    const float* W_ph   = (const float*)d_in[2];
    const float* W_g    = (const float*)d_in[3];
    const float* W_attn = (const float*)d_in[4];
    const float* sigma  = (const float*)d_in[5];
    float* out = (float*)d_out;

    const int B = 16;
    unsigned short* thT  = (unsigned short*)d_ws;              // B*N*8
    unsigned short* phiP = thT + (size_t)B * NN * 8;           // B*M*8
    unsigned short* gP   = phiP + (size_t)B * MM * 8;          // B*32*M

    prep_kernel<<<dim3(32, 16), 256, 0, stream>>>(x, W_th, W_ph, W_g,
                                                  thT, phiP, gP);
    attn_mfma<<<dim3(64, 16), 256, 0, stream>>>(thT, phiP, gP, x,
                                                W_attn, sigma, out);
}